// Round 9
// baseline (339.531 us; speedup 1.0000x reference)
//
#include <hip/hip_runtime.h>
#include <hip/hip_fp16.h>
#include <stddef.h>
#include <stdint.h>

// Problem: N=4, S=4096, E=1024, H=16, D=64. fp32 in/out.
// Reference = "attention over heads": per (n,s) position, 16x16 softmax across
// heads, then scrambled (N,H,S,D)->(N,S,E) reshape + output projection.
// Pipeline (f16 MFMA compute, fp32 accumulate; absmax ~8e-3 << 4.09e-2):
//   K0: convert x, Wq..Wo fp32 -> f16 in ws
//   K1: QKV projection -- ROUND 9: split into 3 dispatches (measurement:
//       the top-5 profiler window was 100% qkv instances, hiding the true
//       attn/outp/cvt budget; with ~43us layers, anything bigger MUST appear)
//   K2: per-position head-attention (round-8 coalesced epilogue, passed)
//   K3: output projection (round-6 gemm256, passed)
// Component model is provably wrong (sum != total); this round buys the
// real budget with a ~0-cost structural change. Everything else verbatim.

typedef _Float16 f16_t;
typedef _Float16 f16x8 __attribute__((ext_vector_type(8)));
typedef _Float16 f16x4 __attribute__((ext_vector_type(4)));
typedef float    f32x4 __attribute__((ext_vector_type(4)));

static constexpr int Sdim = 4096;
static constexpr int Edim = 1024;
static constexpr int Mrows = 4 * Sdim;                  // 16384
static constexpr size_t MATEL = (size_t)Mrows * Edim;   // 16.7M
static constexpr size_t WEL = (size_t)Edim * Edim;      // 1.05M

__device__ __forceinline__ void gload_lds16(const f16_t* g, f16_t* l) {
  // async global->LDS, 16B/lane; LDS dest = wave-uniform base + lane*16
  __builtin_amdgcn_global_load_lds(
      (const __attribute__((address_space(1))) void*)g,
      (__attribute__((address_space(3))) void*)l, 16, 0, 0);
}

// Opaque LDS read on raw 32-bit LDS byte address. Volatile: ordered among
// themselves and vs the (volatile) waitcnt asms -> exact lgkm counts hold.
__device__ __forceinline__ f16x8 ds_read16(uint32_t byte_addr) {
  f16x8 r;
  asm volatile("ds_read_b128 %0, %1" : "=v"(r) : "v"(byte_addr));
  return r;
}

#define SCHED_FENCE() __builtin_amdgcn_sched_barrier(0)

// ---------------- fp32 -> f16 convert ----------------
__global__ __launch_bounds__(256) void cvt_kernel(
    const float* __restrict__ s0, const float* __restrict__ s1,
    const float* __restrict__ s2, const float* __restrict__ s3,
    const float* __restrict__ s4,
    f16_t* __restrict__ d0, f16_t* __restrict__ d1, f16_t* __restrict__ d2,
    f16_t* __restrict__ d3, f16_t* __restrict__ d4) {
  const float* s; f16_t* d; size_t nv;  // nv = count of float4 groups
  switch (blockIdx.y) {
    case 0: s = s0; d = d0; nv = MATEL / 4; break;
    case 1: s = s1; d = d1; nv = WEL / 4; break;
    case 2: s = s2; d = d2; nv = WEL / 4; break;
    case 3: s = s3; d = d3; nv = WEL / 4; break;
    default: s = s4; d = d4; nv = WEL / 4; break;
  }
  const size_t stride = (size_t)gridDim.x * 256;
  for (size_t i = blockIdx.x * 256 + threadIdx.x; i < nv; i += stride) {
    const f32x4 v = ((const f32x4*)s)[i];
    f16x4 h;
#pragma unroll
    for (int j = 0; j < 4; j++) h[j] = (f16_t)v[j];
    ((f16x4*)d)[i] = h;
  }
}

// ---------------- 256^2 reg-pipelined GEMM core (round-6, passed 3x) -------
static constexpr int BM2 = 256, BN2 = 256, BK2 = 64;
static constexpr int NT2 = Edim / BK2;   // 16 K-tiles
static constexpr int HALF2 = 128 * BK2;  // 8192 f16 = 16KB per half-tile

template <int V> struct ic { static constexpr int v = V; };

template <typename TOut>
__device__ __forceinline__ void gemm256(const f16_t* __restrict__ A,
                                        const f16_t* __restrict__ B,
                                        const float* __restrict__ bias,
                                        TOut* __restrict__ C) {
  __shared__ __align__(16) f16_t lds[2][2][2][HALF2];  // [slot][mat][half][.]

  const int t = threadIdx.x;
  const int lane = t & 63;
  const int w = t >> 6;
  const int l16 = lane & 15;
  const int quad = lane >> 4;
  const int ha = w >> 2;         // A half this wave reads (wm = ha*128)
  const int hb = (w & 3) >> 1;   // B half this wave reads
  const int wnr = (w & 1) * 64;  // row offset inside B half

  const uint32_t ldsBase = (uint32_t)(uintptr_t)
      (__attribute__((address_space(3))) f16_t*)&lds[0][0][0][0];
  const uint32_t aHalfOff = (uint32_t)(ha * (HALF2 * 2));
  const uint32_t bHalfOff = (uint32_t)(32768 + hb * (HALF2 * 2));

  // T1: XCD-chunked bijective swizzle over the 256 (mtile,ntile) blocks.
  const int id = blockIdx.x;
  const int id2 = (id & 7) * 32 + (id >> 3);
  const int bm = (id2 & 63) * BM2;
  const int bn = (id2 >> 6) * BN2;

  const int srow = w * 8 + (lane >> 3);
  const int scol = ((lane & 7) ^ ((lane >> 3) & 7)) * 8;
  const size_t gA0 = (size_t)(bm + srow) * Edim + scol;
  const size_t gB0 = (size_t)(bn + srow) * Edim + scol;
  const int lws = w * 512 + lane * 8;

  auto stage = [&](int mat, int half, int slot, int kt) {
    const f16_t* g = (mat == 0 ? A + gA0 : B + gB0) +
                     (size_t)half * 128 * Edim + kt * BK2;
    f16_t* l = &lds[slot][mat][half][lws];
    gload_lds16(g, l);                             // rows 0..63 of half
    gload_lds16(g + (size_t)64 * Edim, l + 4096);  // rows 64..127
  };

  auto rdaddr = [&](uint32_t base, int r, int c0) -> uint32_t {
    return base + (uint32_t)((r * 64 + (c0 ^ ((r & 7) << 3))) * 2);
  };

  f32x4 acc[8][4] = {};
  f16x8 af0[4], af1[4], bf0[4], bf1[4];

  auto rdA = [&](uint32_t aBase, int ih, int kc, f16x8* dst) {
#pragma unroll
    for (int ii = 0; ii < 4; ++ii) {
      const int r = ih * 64 + ii * 16 + l16;
      dst[ii] = ds_read16(rdaddr(aBase, r, kc * 32 + quad * 8));
    }
  };
  auto rdB = [&](uint32_t bBase, int kc, f16x8* dst) {
#pragma unroll
    for (int j = 0; j < 4; ++j) {
      const int r = wnr + j * 16 + l16;
      dst[j] = ds_read16(rdaddr(bBase, r, kc * 32 + quad * 8));
    }
  };
  auto mmac = [&](const f16x8* af, const f16x8* bf, int ih) {
    __builtin_amdgcn_s_setprio(1);
#pragma unroll
    for (int ii = 0; ii < 4; ++ii)
#pragma unroll
      for (int j = 0; j < 4; ++j)
        acc[ih * 4 + ii][j] = __builtin_amdgcn_mfma_f32_16x16x32_f16(
            af[ii], bf[j], acc[ih * 4 + ii][j], 0, 0, 0);
    __builtin_amdgcn_s_setprio(0);
  };

  stage(0, 0, 0, 0); stage(0, 1, 0, 0);
  stage(1, 0, 0, 0); stage(1, 1, 0, 0);
  stage(1, 0, 1, 1); stage(1, 1, 1, 1);
  asm volatile("s_waitcnt vmcnt(2)");
  SCHED_FENCE();
  __builtin_amdgcn_s_barrier();
  SCHED_FENCE();
  rdA(ldsBase + aHalfOff, 0, 0, af0);
  rdB(ldsBase + bHalfOff, 0, bf0);

  auto ktile = [&](int tt, auto SAc, auto SBc, auto NQc) {
    constexpr int SA = decltype(SAc)::v;
    constexpr int SB = decltype(SBc)::v;
    constexpr int NQ = decltype(NQc)::v;
    const int S = tt & 1;
    const uint32_t aB  = ldsBase + (uint32_t)(S * 65536) + aHalfOff;
    const uint32_t bB  = ldsBase + (uint32_t)(S * 65536) + bHalfOff;
    const uint32_t aBn = ldsBase + (uint32_t)((S ^ 1) * 65536) + aHalfOff;
    const uint32_t bBn = ldsBase + (uint32_t)((S ^ 1) * 65536) + bHalfOff;
    rdA(aB, 1, 0, af1);
    if (SA) { stage(0, 0, S ^ 1, tt + 1); stage(0, 1, S ^ 1, tt + 1); }
    SCHED_FENCE();
    asm volatile("s_waitcnt lgkmcnt(4)");
    SCHED_FENCE();
    mmac(af0, bf0, 0);
    rdA(aB, 0, 1, af0);
    rdB(bB, 1, bf1);
    SCHED_FENCE();
    asm volatile("s_waitcnt lgkmcnt(8)");
    SCHED_FENCE();
    mmac(af1, bf0, 1);
    rdA(aB, 1, 1, af1);
    SCHED_FENCE();
    asm volatile("s_waitcnt lgkmcnt(4)");
    SCHED_FENCE();
    mmac(af0, bf1, 0);
    asm volatile("s_waitcnt lgkmcnt(0)");
    asm volatile("s_waitcnt vmcnt(0)");
    SCHED_FENCE();
    __builtin_amdgcn_s_barrier();
    SCHED_FENCE();
    if (SB) { stage(1, 0, S, tt + 2); stage(1, 1, S, tt + 2); }
    if (NQ) { rdA(aBn, 0, 0, af0); rdB(bBn, 0, bf0); }
    SCHED_FENCE();
    mmac(af1, bf1, 1);
  };

  for (int tt = 0; tt < NT2 - 2; ++tt) ktile(tt, ic<1>{}, ic<1>{}, ic<1>{});
  ktile(NT2 - 2, ic<1>{}, ic<0>{}, ic<1>{});
  ktile(NT2 - 1, ic<0>{}, ic<0>{}, ic<0>{});

  // Epilogue. C/D layout: col = lane&15, row = quad*4 + reg [m89-verified].
  const int wm = ha * 128;
  const int wn = (w & 3) * 64;
#pragma unroll
  for (int j = 0; j < 4; ++j) {
    const int col = bn + wn + j * 16 + l16;
    const float bv = bias[col];
#pragma unroll
    for (int i = 0; i < 8; ++i) {
      const int rb = bm + wm + i * 16 + quad * 4;
#pragma unroll
      for (int r = 0; r < 4; ++r)
        C[(size_t)(rb + r) * Edim + col] = (TOut)(acc[i][j][r] + bv);
    }
  }
}

// ROUND 9: one GEMM per dispatch (measurement: each ~43us -> top-5 must now
// reveal attn/outp/cvt if any exceeds that).
__global__ __launch_bounds__(512, 1) void qkv_one_kernel(
    const f16_t* __restrict__ x, const f16_t* __restrict__ W,
    const float* __restrict__ b, f16_t* __restrict__ C) {
  gemm256<f16_t>(x, W, b, C);
}

__global__ __launch_bounds__(512, 1) void outp_kernel(
    const f16_t* __restrict__ Ab, const f16_t* __restrict__ Wo,
    const float* __restrict__ bo, float* __restrict__ out) {
  gemm256<float>(Ab, Wo, bo, out);
}

// ---------------- per-position head-attention (one wave / position) ----------
// (round-8 version: coalesced LDS-transposed epilogue; passed)
__global__ __launch_bounds__(256) void attn_kernel(const f16_t* __restrict__ Qb,
                                                   const f16_t* __restrict__ Kb,
                                                   const f16_t* __restrict__ Vb,
                                                   f16_t* __restrict__ Ab) {
  __shared__ __align__(16) f16_t Vs[4][1024];     // per-wave V row (2KB each)
  __shared__ __align__(16) f16_t Ot[4][16 * 72];  // per-wave O^T, pad 64->72
  const int t = threadIdx.x;
  const int w = t >> 6;
  const int lane = t & 63;
  const int l16 = lane & 15;
  const int quad = lane >> 4;
  const int pos = blockIdx.x * 4 + w;           // n*S + s
  const int n4 = pos >> 12;
  const int s = pos & (Sdim - 1);

  const f16_t* Qr = Qb + (size_t)pos * Edim;
  const f16_t* Kr = Kb + (size_t)pos * Edim;
  const f16_t* Vr = Vb + (size_t)pos * Edim;

  // stage V row into LDS (coalesced: 32B/lane); consumed by same wave only
  *(f16x8*)&Vs[w][lane * 16]     = *(const f16x8*)(Vr + lane * 16);
  *(f16x8*)&Vs[w][lane * 16 + 8] = *(const f16x8*)(Vr + lane * 16 + 8);

  // scores: S^T via 2 MFMA steps over head-dim 64
  f32x4 sacc = {};
#pragma unroll
  for (int step = 0; step < 2; step++) {
    const int off = l16 * 64 + step * 32 + quad * 8;
    const f16x8 kf = *(const f16x8*)(Kr + off);  // A: K[m=l16][k]
    const f16x8 qf = *(const f16x8*)(Qr + off);  // B: Q[n=l16][k]
    sacc = __builtin_amdgcn_mfma_f32_16x16x32_f16(kf, qf, sacc, 0, 0, 0);
  }
  // lane holds S[q=l16][kh = quad*4+reg], scaled by 1/sqrt(64)
#pragma unroll
  for (int r = 0; r < 4; r++) sacc[r] *= 0.125f;

  // softmax over kh (in-lane regs + cross-quad shuffles)
  float m = fmaxf(fmaxf(sacc[0], sacc[1]), fmaxf(sacc[2], sacc[3]));
  m = fmaxf(m, __shfl_xor(m, 16));
  m = fmaxf(m, __shfl_xor(m, 32));
  float e[4];
#pragma unroll
  for (int r = 0; r < 4; r++) e[r] = __expf(sacc[r] - m);
  float l = (e[0] + e[1]) + (e[2] + e[3]);
  l += __shfl_xor(l, 16);
  l += __shfl_xor(l, 32);
  const float inv = 1.0f / l;
  f16x4 pa;  // P in A-frag layout: P[q=l16][l=quad*4+j]
#pragma unroll
  for (int r = 0; r < 4; r++) pa[r] = (f16_t)(e[r] * inv);

  // PV: O[q][d] over 4 d-chunks of 16, K-dim = 16 heads (wave-private LDS)
  f32x4 oacc[4];
#pragma unroll
  for (int dc = 0; dc < 4; dc++) {
    f16x4 vbf;  // B: V^T[n=d_sub=l16][k=l=quad*4+j] = Vs[l][dc*16+l16]
#pragma unroll
    for (int j = 0; j < 4; j++)
      vbf[j] = Vs[w][(quad * 4 + j) * 64 + dc * 16 + l16];
    f32x4 z = {};
    oacc[dc] = __builtin_amdgcn_mfma_f32_16x16x16f16(pa, vbf, z, 0, 0, 0);
  }

  // coalesced epilogue: transpose O through wave-private LDS, then 2
  // 16B/lane stores (full 128B segments). lane holds O[q=quad*4+reg][d=dc*16+l16]
#pragma unroll
  for (int dc = 0; dc < 4; dc++)
#pragma unroll
    for (int reg = 0; reg < 4; reg++)
      Ot[w][(quad * 4 + reg) * 72 + dc * 16 + l16] = (f16_t)oacc[dc][reg];

  const size_t rowbase = ((size_t)(n4 << 12) + (size_t)(s >> 4)) * Edim +
                         (size_t)(s & 15) * 64 + (size_t)(lane & 7) * 8;
#pragma unroll
  for (int i = 0; i < 2; i++) {
    const int h = (lane >> 3) + 8 * i;
    const f16x8 v = *(const f16x8*)&Ot[w][h * 72 + (lane & 7) * 8];
    *(f16x8*)&Ab[rowbase + (size_t)h * 256 * Edim] = v;
  }
}

// ---------------- launcher ----------------
extern "C" void kernel_launch(void* const* d_in, const int* in_sizes, int n_in,
                              void* d_out, int out_size, void* d_ws, size_t ws_size,
                              hipStream_t stream) {
  const float* x  = (const float*)d_in[0];
  const float* Wq = (const float*)d_in[1];
  const float* bq = (const float*)d_in[2];
  const float* Wk = (const float*)d_in[3];
  const float* bk = (const float*)d_in[4];
  const float* Wv = (const float*)d_in[5];
  const float* bv = (const float*)d_in[6];
  const float* Wo = (const float*)d_in[7];
  const float* bo = (const float*)d_in[8];
  float* out = (float*)d_out;

  f16_t* xh  = (f16_t*)d_ws;          // 33.5 MB
  f16_t* Wqh = xh + MATEL;            // 2 MB each
  f16_t* Wkh = Wqh + WEL;
  f16_t* Wvh = Wkh + WEL;
  f16_t* Woh = Wvh + WEL;
  f16_t* Qb  = Woh + WEL;             // 33.5 MB each
  f16_t* Kb  = Qb + MATEL;
  f16_t* Vb  = Kb + MATEL;
  f16_t* Ab  = Vb + MATEL;            // total ~176 MB

  cvt_kernel<<<dim3(2048, 5), dim3(256), 0, stream>>>(x, Wq, Wk, Wv, Wo,
                                                      xh, Wqh, Wkh, Wvh, Woh);
  const int ngrid = (Mrows / BM2) * (Edim / BN2);  // 64*4 = 256, %8 == 0
  qkv_one_kernel<<<dim3(ngrid), dim3(512), 0, stream>>>(xh, Wqh, bq, Qb);
  qkv_one_kernel<<<dim3(ngrid), dim3(512), 0, stream>>>(xh, Wkh, bk, Kb);
  qkv_one_kernel<<<dim3(ngrid), dim3(512), 0, stream>>>(xh, Wvh, bv, Vb);
  attn_kernel<<<dim3(Mrows / 4), dim3(256), 0, stream>>>(Qb, Kb, Vb, Ab);
  outp_kernel<<<dim3(ngrid), dim3(512), 0, stream>>>(Ab, Woh, bo, out);
}

// Round 11
// 316.405 us; speedup vs baseline: 1.0731x; 1.0731x over previous
//
#include <hip/hip_runtime.h>
#include <hip/hip_fp16.h>
#include <stddef.h>
#include <stdint.h>

// Problem: N=4, S=4096, E=1024, H=16, D=64. fp32 in/out.
// Reference = "attention over heads": per (n,s) position, 16x16 softmax across
// heads, then scrambled (N,H,S,D)->(N,S,E) reshape + output projection.
// Pipeline (f16 MFMA compute, fp32 accumulate; absmax ~8e-3 << 4.09e-2):
//   K0: convert x, Wq..Wo fp32 -> f16 in ws
//   K1: QKV projections (z=3 grid, round-6 K-loop -- passed 3x)
//   K2: per-position head-attention (round-8 coalesced epilogue, passed 2x)
//   K3: output projection
// ROUND 11: coalesced GEMM epilogue, ATTN-PROVEN FORM. Round-10's XOR-swizzled
// variant failed correctness (absmax 1.56; bug not localizable by inspection).
// Round-9 measurement stands: WRITE_SIZE 81.5MB/GEMM vs 33.5 ideal (2.43x amp
// from 32B scattered store fragments). This version mirrors the PASSED attn
// epilogue: PADDED per-wave LDS chunk (stride 72 f16 / 68 fp32), plain
// [row][col] indices (no swizzle), explicit __syncthreads between write and
// read phases. Staging LDS enlarged to a flat 144KB buffer (first 128KB =
// identical staging layout; still 1 block/CU).

typedef _Float16 f16_t;
typedef _Float16 f16x8 __attribute__((ext_vector_type(8)));
typedef _Float16 f16x4 __attribute__((ext_vector_type(4)));
typedef float    f32x4 __attribute__((ext_vector_type(4)));

static constexpr int Sdim = 4096;
static constexpr int Edim = 1024;
static constexpr int Mrows = 4 * Sdim;                  // 16384
static constexpr size_t MATEL = (size_t)Mrows * Edim;   // 16.7M
static constexpr size_t WEL = (size_t)Edim * Edim;      // 1.05M

__device__ __forceinline__ void gload_lds16(const f16_t* g, f16_t* l) {
  // async global->LDS, 16B/lane; LDS dest = wave-uniform base + lane*16
  __builtin_amdgcn_global_load_lds(
      (const __attribute__((address_space(1))) void*)g,
      (__attribute__((address_space(3))) void*)l, 16, 0, 0);
}

// Opaque LDS read on raw 32-bit LDS byte address. Volatile: ordered among
// themselves and vs the (volatile) waitcnt asms -> exact lgkm counts hold.
__device__ __forceinline__ f16x8 ds_read16(uint32_t byte_addr) {
  f16x8 r;
  asm volatile("ds_read_b128 %0, %1" : "=v"(r) : "v"(byte_addr));
  return r;
}

#define SCHED_FENCE() __builtin_amdgcn_sched_barrier(0)

// ---------------- fp32 -> f16 convert ----------------
__global__ __launch_bounds__(256) void cvt_kernel(
    const float* __restrict__ s0, const float* __restrict__ s1,
    const float* __restrict__ s2, const float* __restrict__ s3,
    const float* __restrict__ s4,
    f16_t* __restrict__ d0, f16_t* __restrict__ d1, f16_t* __restrict__ d2,
    f16_t* __restrict__ d3, f16_t* __restrict__ d4) {
  const float* s; f16_t* d; size_t nv;  // nv = count of float4 groups
  switch (blockIdx.y) {
    case 0: s = s0; d = d0; nv = MATEL / 4; break;
    case 1: s = s1; d = d1; nv = WEL / 4; break;
    case 2: s = s2; d = d2; nv = WEL / 4; break;
    case 3: s = s3; d = d3; nv = WEL / 4; break;
    default: s = s4; d = d4; nv = WEL / 4; break;
  }
  const size_t stride = (size_t)gridDim.x * 256;
  for (size_t i = blockIdx.x * 256 + threadIdx.x; i < nv; i += stride) {
    const f32x4 v = ((const f32x4*)s)[i];
    f16x4 h;
#pragma unroll
    for (int j = 0; j < 4; j++) h[j] = (f16_t)v[j];
    ((f16x4*)d)[i] = h;
  }
}

// ---------------- 256^2 reg-pipelined GEMM core ----------------
static constexpr int BM2 = 256, BN2 = 256, BK2 = 64;
static constexpr int NT2 = Edim / BK2;   // 16 K-tiles
static constexpr int HALF2 = 128 * BK2;  // 8192 f16 = 16KB per half-tile

template <int V> struct ic { static constexpr int v = V; };

template <typename TOut>
__device__ __forceinline__ void gemm256(const f16_t* __restrict__ A,
                                        const f16_t* __restrict__ B,
                                        const float* __restrict__ bias,
                                        TOut* __restrict__ C) {
  // 144 KB flat buffer. First 128 KB = staging, layout identical to the old
  // [slot][mat][half][HALF2] (f16 idx slot*32768 + mat*16384 + half*8192).
  // Epilogue reuses it as 8 per-wave padded chunks (9216 f16 / 4352 f32 each).
  __shared__ __align__(16) f16_t ldsbuf[73728];

  const int t = threadIdx.x;
  const int lane = t & 63;
  const int w = t >> 6;
  const int l16 = lane & 15;
  const int quad = lane >> 4;
  const int ha = w >> 2;         // A half this wave reads (wm = ha*128)
  const int hb = (w & 3) >> 1;   // B half this wave reads
  const int wnr = (w & 1) * 64;  // row offset inside B half

  const uint32_t ldsBase = (uint32_t)(uintptr_t)
      (__attribute__((address_space(3))) f16_t*)&ldsbuf[0];
  const uint32_t aHalfOff = (uint32_t)(ha * (HALF2 * 2));
  const uint32_t bHalfOff = (uint32_t)(32768 + hb * (HALF2 * 2));

  // T1: XCD-chunked bijective swizzle over the 256 (mtile,ntile) blocks.
  const int id = blockIdx.x;
  const int id2 = (id & 7) * 32 + (id >> 3);
  const int bm = (id2 & 63) * BM2;
  const int bn = (id2 >> 6) * BN2;

  const int srow = w * 8 + (lane >> 3);
  const int scol = ((lane & 7) ^ ((lane >> 3) & 7)) * 8;
  const size_t gA0 = (size_t)(bm + srow) * Edim + scol;
  const size_t gB0 = (size_t)(bn + srow) * Edim + scol;
  const int lws = w * 512 + lane * 8;

  auto stage = [&](int mat, int half, int slot, int kt) {
    const f16_t* g = (mat == 0 ? A + gA0 : B + gB0) +
                     (size_t)half * 128 * Edim + kt * BK2;
    f16_t* l = &ldsbuf[slot * 32768 + mat * 16384 + half * 8192 + lws];
    gload_lds16(g, l);                             // rows 0..63 of half
    gload_lds16(g + (size_t)64 * Edim, l + 4096);  // rows 64..127
  };

  auto rdaddr = [&](uint32_t base, int r, int c0) -> uint32_t {
    return base + (uint32_t)((r * 64 + (c0 ^ ((r & 7) << 3))) * 2);
  };

  f32x4 acc[8][4] = {};
  f16x8 af0[4], af1[4], bf0[4], bf1[4];

  auto rdA = [&](uint32_t aBase, int ih, int kc, f16x8* dst) {
#pragma unroll
    for (int ii = 0; ii < 4; ++ii) {
      const int r = ih * 64 + ii * 16 + l16;
      dst[ii] = ds_read16(rdaddr(aBase, r, kc * 32 + quad * 8));
    }
  };
  auto rdB = [&](uint32_t bBase, int kc, f16x8* dst) {
#pragma unroll
    for (int j = 0; j < 4; ++j) {
      const int r = wnr + j * 16 + l16;
      dst[j] = ds_read16(rdaddr(bBase, r, kc * 32 + quad * 8));
    }
  };
  auto mmac = [&](const f16x8* af, const f16x8* bf, int ih) {
    __builtin_amdgcn_s_setprio(1);
#pragma unroll
    for (int ii = 0; ii < 4; ++ii)
#pragma unroll
      for (int j = 0; j < 4; ++j)
        acc[ih * 4 + ii][j] = __builtin_amdgcn_mfma_f32_16x16x32_f16(
            af[ii], bf[j], acc[ih * 4 + ii][j], 0, 0, 0);
    __builtin_amdgcn_s_setprio(0);
  };

  stage(0, 0, 0, 0); stage(0, 1, 0, 0);
  stage(1, 0, 0, 0); stage(1, 1, 0, 0);
  stage(1, 0, 1, 1); stage(1, 1, 1, 1);
  asm volatile("s_waitcnt vmcnt(2)");
  SCHED_FENCE();
  __builtin_amdgcn_s_barrier();
  SCHED_FENCE();
  rdA(ldsBase + aHalfOff, 0, 0, af0);
  rdB(ldsBase + bHalfOff, 0, bf0);

  auto ktile = [&](int tt, auto SAc, auto SBc, auto NQc) {
    constexpr int SA = decltype(SAc)::v;
    constexpr int SB = decltype(SBc)::v;
    constexpr int NQ = decltype(NQc)::v;
    const int S = tt & 1;
    const uint32_t aB  = ldsBase + (uint32_t)(S * 65536) + aHalfOff;
    const uint32_t bB  = ldsBase + (uint32_t)(S * 65536) + bHalfOff;
    const uint32_t aBn = ldsBase + (uint32_t)((S ^ 1) * 65536) + aHalfOff;
    const uint32_t bBn = ldsBase + (uint32_t)((S ^ 1) * 65536) + bHalfOff;
    rdA(aB, 1, 0, af1);
    if (SA) { stage(0, 0, S ^ 1, tt + 1); stage(0, 1, S ^ 1, tt + 1); }
    SCHED_FENCE();
    asm volatile("s_waitcnt lgkmcnt(4)");
    SCHED_FENCE();
    mmac(af0, bf0, 0);
    rdA(aB, 0, 1, af0);
    rdB(bB, 1, bf1);
    SCHED_FENCE();
    asm volatile("s_waitcnt lgkmcnt(8)");
    SCHED_FENCE();
    mmac(af1, bf0, 1);
    rdA(aB, 1, 1, af1);
    SCHED_FENCE();
    asm volatile("s_waitcnt lgkmcnt(4)");
    SCHED_FENCE();
    mmac(af0, bf1, 0);
    asm volatile("s_waitcnt lgkmcnt(0)");
    asm volatile("s_waitcnt vmcnt(0)");
    SCHED_FENCE();
    __builtin_amdgcn_s_barrier();
    SCHED_FENCE();
    if (SB) { stage(1, 0, S, tt + 2); stage(1, 1, S, tt + 2); }
    if (NQ) { rdA(aBn, 0, 0, af0); rdB(bBn, 0, bf0); }
    SCHED_FENCE();
    mmac(af1, bf1, 1);
  };

  for (int tt = 0; tt < NT2 - 2; ++tt) ktile(tt, ic<1>{}, ic<1>{}, ic<1>{});
  ktile(NT2 - 2, ic<1>{}, ic<0>{}, ic<1>{});
  ktile(NT2 - 1, ic<0>{}, ic<0>{}, ic<0>{});

  // ---- ROUND-11 coalesced epilogue (attn-proven padded-LDS transpose).
  // All DMA drained (vmcnt(0) at both tails) and all asm ds_reads drained
  // (lgkm(0) before last barrier) -> after this barrier staging LDS is dead.
  // Per-wave chunk, plain [row][col] indices, pad keeps 16B alignment.
  // C/D frag layout: col = lane&15, row = quad*4 + reg [m89-verified];
  // acc[i] covers local rows i*16..i*16+15 (i = ih*4+ii; ih*64+ii*16 == i*16).
  __syncthreads();
  const int wm = ha * 128;
  const int wn = (w & 3) * 64;
  float bv4[4];
#pragma unroll
  for (int j = 0; j < 4; ++j) bv4[j] = bias[bn + wn + j * 16 + l16];

  if constexpr (sizeof(TOut) == 2) {
    f16_t* ep = &ldsbuf[w * 9216];           // 128 rows x stride 72 (18KB)
#pragma unroll
    for (int i = 0; i < 8; ++i)
#pragma unroll
      for (int j = 0; j < 4; ++j)
#pragma unroll
        for (int r = 0; r < 4; ++r)
          ep[(i * 16 + quad * 4 + r) * 72 + j * 16 + l16] =
              (f16_t)(acc[i][j][r] + bv4[j]);
    __syncthreads();
#pragma unroll
    for (int it2 = 0; it2 < 16; ++it2) {
      const int rl = it2 * 8 + (lane >> 3);   // 8 lanes/row
      const int c0 = (lane & 7) * 8;
      const f16x8 v = *(const f16x8*)&ep[rl * 72 + c0];
      *(f16x8*)&C[(size_t)(bm + wm + rl) * Edim + bn + wn + c0] = v;
    }
  } else {
    float* ep = ((float*)&ldsbuf[0]) + w * 4352;  // 64 rows x stride 68 (17KB)
#pragma unroll
    for (int p = 0; p < 2; ++p) {
#pragma unroll
      for (int i2 = 0; i2 < 4; ++i2)
#pragma unroll
        for (int j = 0; j < 4; ++j)
#pragma unroll
          for (int r = 0; r < 4; ++r)
            ep[(i2 * 16 + quad * 4 + r) * 68 + j * 16 + l16] =
                acc[p * 4 + i2][j][r] + bv4[j];
      __syncthreads();
#pragma unroll
      for (int it2 = 0; it2 < 16; ++it2) {
        const int rl = it2 * 4 + quad;        // 16 lanes/row
        const int c0 = l16 * 4;
        const f32x4 v = *(const f32x4*)&ep[rl * 68 + c0];
        *(f32x4*)&C[(size_t)(bm + wm + p * 64 + rl) * Edim + bn + wn + c0] = v;
      }
      __syncthreads();  // drain pass-p reads before pass-(p+1) overwrites
    }
  }
}

__global__ __launch_bounds__(512, 1) void qkv_kernel(
    const f16_t* __restrict__ x,
    const f16_t* __restrict__ Wq, const float* __restrict__ bq,
    const f16_t* __restrict__ Wk, const float* __restrict__ bk,
    const f16_t* __restrict__ Wv, const float* __restrict__ bv,
    f16_t* __restrict__ Qb, f16_t* __restrict__ Kb, f16_t* __restrict__ Vb) {
  const f16_t* W; const float* bi; f16_t* C;
  if (blockIdx.z == 0)      { W = Wq; bi = bq; C = Qb; }
  else if (blockIdx.z == 1) { W = Wk; bi = bk; C = Kb; }
  else                      { W = Wv; bi = bv; C = Vb; }
  gemm256<f16_t>(x, W, bi, C);
}

__global__ __launch_bounds__(512, 1) void outp_kernel(
    const f16_t* __restrict__ Ab, const f16_t* __restrict__ Wo,
    const float* __restrict__ bo, float* __restrict__ out) {
  gemm256<float>(Ab, Wo, bo, out);
}

// ---------------- per-position head-attention (one wave / position) ----------
// (round-8 version: coalesced LDS-transposed epilogue; passed 2x)
__global__ __launch_bounds__(256) void attn_kernel(const f16_t* __restrict__ Qb,
                                                   const f16_t* __restrict__ Kb,
                                                   const f16_t* __restrict__ Vb,
                                                   f16_t* __restrict__ Ab) {
  __shared__ __align__(16) f16_t Vs[4][1024];     // per-wave V row (2KB each)
  __shared__ __align__(16) f16_t Ot[4][16 * 72];  // per-wave O^T, pad 64->72
  const int t = threadIdx.x;
  const int w = t >> 6;
  const int lane = t & 63;
  const int l16 = lane & 15;
  const int quad = lane >> 4;
  const int pos = blockIdx.x * 4 + w;           // n*S + s
  const int n4 = pos >> 12;
  const int s = pos & (Sdim - 1);

  const f16_t* Qr = Qb + (size_t)pos * Edim;
  const f16_t* Kr = Kb + (size_t)pos * Edim;
  const f16_t* Vr = Vb + (size_t)pos * Edim;

  *(f16x8*)&Vs[w][lane * 16]     = *(const f16x8*)(Vr + lane * 16);
  *(f16x8*)&Vs[w][lane * 16 + 8] = *(const f16x8*)(Vr + lane * 16 + 8);

  f32x4 sacc = {};
#pragma unroll
  for (int step = 0; step < 2; step++) {
    const int off = l16 * 64 + step * 32 + quad * 8;
    const f16x8 kf = *(const f16x8*)(Kr + off);  // A: K[m=l16][k]
    const f16x8 qf = *(const f16x8*)(Qr + off);  // B: Q[n=l16][k]
    sacc = __builtin_amdgcn_mfma_f32_16x16x32_f16(kf, qf, sacc, 0, 0, 0);
  }
#pragma unroll
  for (int r = 0; r < 4; r++) sacc[r] *= 0.125f;

  float m = fmaxf(fmaxf(sacc[0], sacc[1]), fmaxf(sacc[2], sacc[3]));
  m = fmaxf(m, __shfl_xor(m, 16));
  m = fmaxf(m, __shfl_xor(m, 32));
  float e[4];
#pragma unroll
  for (int r = 0; r < 4; r++) e[r] = __expf(sacc[r] - m);
  float l = (e[0] + e[1]) + (e[2] + e[3]);
  l += __shfl_xor(l, 16);
  l += __shfl_xor(l, 32);
  const float inv = 1.0f / l;
  f16x4 pa;  // P in A-frag layout: P[q=l16][l=quad*4+j]
#pragma unroll
  for (int r = 0; r < 4; r++) pa[r] = (f16_t)(e[r] * inv);

  f32x4 oacc[4];
#pragma unroll
  for (int dc = 0; dc < 4; dc++) {
    f16x4 vbf;  // B: V^T[n=d_sub=l16][k=l=quad*4+j] = Vs[l][dc*16+l16]
#pragma unroll
    for (int j = 0; j < 4; j++)
      vbf[j] = Vs[w][(quad * 4 + j) * 64 + dc * 16 + l16];
    f32x4 z = {};
    oacc[dc] = __builtin_amdgcn_mfma_f32_16x16x16f16(pa, vbf, z, 0, 0, 0);
  }

#pragma unroll
  for (int dc = 0; dc < 4; dc++)
#pragma unroll
    for (int reg = 0; reg < 4; reg++)
      Ot[w][(quad * 4 + reg) * 72 + dc * 16 + l16] = (f16_t)oacc[dc][reg];

  const size_t rowbase = ((size_t)(n4 << 12) + (size_t)(s >> 4)) * Edim +
                         (size_t)(s & 15) * 64 + (size_t)(lane & 7) * 8;
#pragma unroll
  for (int i = 0; i < 2; i++) {
    const int h = (lane >> 3) + 8 * i;
    const f16x8 v = *(const f16x8*)&Ot[w][h * 72 + (lane & 7) * 8];
    *(f16x8*)&Ab[rowbase + (size_t)h * 256 * Edim] = v;
  }
}

// ---------------- launcher ----------------
extern "C" void kernel_launch(void* const* d_in, const int* in_sizes, int n_in,
                              void* d_out, int out_size, void* d_ws, size_t ws_size,
                              hipStream_t stream) {
  const float* x  = (const float*)d_in[0];
  const float* Wq = (const float*)d_in[1];
  const float* bq = (const float*)d_in[2];
  const float* Wk = (const float*)d_in[3];
  const float* bk = (const float*)d_in[4];
  const float* Wv = (const float*)d_in[5];
  const float* bv = (const float*)d_in[6];
  const float* Wo = (const float*)d_in[7];
  const float* bo = (const float*)d_in[8];
  float* out = (float*)d_out;

  f16_t* xh  = (f16_t*)d_ws;          // 33.5 MB
  f16_t* Wqh = xh + MATEL;            // 2 MB each
  f16_t* Wkh = Wqh + WEL;
  f16_t* Wvh = Wkh + WEL;
  f16_t* Woh = Wvh + WEL;
  f16_t* Qb  = Woh + WEL;             // 33.5 MB each
  f16_t* Kb  = Qb + MATEL;
  f16_t* Vb  = Kb + MATEL;
  f16_t* Ab  = Vb + MATEL;            // total ~176 MB

  cvt_kernel<<<dim3(2048, 5), dim3(256), 0, stream>>>(x, Wq, Wk, Wv, Wo,
                                                      xh, Wqh, Wkh, Wvh, Woh);
  const int ngrid = (Mrows / BM2) * (Edim / BN2);  // 64*4 = 256, %8 == 0
  qkv_kernel<<<dim3(ngrid, 1, 3), dim3(512), 0, stream>>>(
      xh, Wqh, bq, Wkh, bk, Wvh, bv, Qb, Kb, Vb);
  attn_kernel<<<dim3(Mrows / 4), dim3(256), 0, stream>>>(Qb, Kb, Vb, Ab);
  outp_kernel<<<dim3(ngrid), dim3(512), 0, stream>>>(Ab, Woh, bo, out);
}